// Round 2
// baseline (42110.538 us; speedup 1.0000x reference)
//
#include <hip/hip_runtime.h>

#define VOCAB 50257
#define EMBED 512
#define HIDDEN 1024
#define SEQLEN 512
#define XDIM 1024  // 2*EMBED
#define CAND_CAP 2048

typedef unsigned long long u64;
typedef unsigned int u32;
typedef unsigned short u16;

// monotone mapping float -> u32 (order-preserving for all finite floats)
__device__ __forceinline__ u32 fmono(float f) {
  u32 b = __float_as_uint(f);
  return b ^ ((b & 0x80000000u) ? 0xFFFFFFFFu : 0x80000000u);
}

__device__ __forceinline__ float wave_reduce_sum(float v) {
#pragma unroll
  for (int off = 32; off > 0; off >>= 1) v += __shfl_down(v, off);
  return v;
}

__device__ __forceinline__ u64 wave_reduce_max_u64(u64 v) {
#pragma unroll
  for (int off = 32; off > 0; off >>= 1) {
    u64 o = __shfl_down(v, off);
    if (o > v) v = o;
  }
  return v;
}

// fp32 -> bf16 round-to-nearest-even (finite inputs only)
__device__ __forceinline__ u16 f2bf_rne(float f) {
  u32 u = __float_as_uint(f);
  u32 r = (u + 0x7FFFu + ((u >> 16) & 1u)) >> 16;
  return (u16)r;
}

__global__ void init_state(const float* __restrict__ h0, const float* __restrict__ c0,
                           float* __restrict__ hbufs, float* __restrict__ cbufs,
                           u64* __restrict__ partials) {
  int i = threadIdx.x;
  if (i < HIDDEN) {
    hbufs[i] = h0[i];
    cbufs[i] = c0[i];
  }
  if (i < 512) partials[i] = 0ull;  // both parity sets
}

// one-shot fp32 -> bf16 conversion of W_lin into workspace
__global__ __launch_bounds__(256)
void convert_wlin(const float* __restrict__ wlin, u16* __restrict__ wb) {
  const long long i8 = (long long)blockIdx.x * 256 + threadIdx.x;  // group of 8 floats
  const long long n8 = (long long)VOCAB * HIDDEN / 8;
  if (i8 >= n8) return;
  const float4* src = (const float4*)wlin;
  float4 a = src[2 * i8];
  float4 b = src[2 * i8 + 1];
  uint4 o;
  o.x = (u32)f2bf_rne(a.x) | ((u32)f2bf_rne(a.y) << 16);
  o.y = (u32)f2bf_rne(a.z) | ((u32)f2bf_rne(a.w) << 16);
  o.z = (u32)f2bf_rne(b.x) | ((u32)f2bf_rne(b.y) << 16);
  o.w = (u32)f2bf_rne(b.z) | ((u32)f2bf_rne(b.w) << 16);
  ((uint4*)wb)[i8] = o;
}

// ============================ fast path ============================

// LSTM step. 256 blocks x 256 threads. For t>0, first finalizes step t-1's
// argmax: every block redundantly (no cross-block comm) reduces the bf16
// screen partials, scans Lb for candidates within the rigorous bf16 error
// bound, and recomputes candidates exactly in fp32 (identical dot structure
// to round-0, so the token trajectory is unchanged).
__global__ __launch_bounds__(256)
void lstm_step(const float* __restrict__ emb,
               const float* __restrict__ wih, const float* __restrict__ whh,
               const float* __restrict__ bih, const float* __restrict__ bhh,
               const int* __restrict__ seq,
               const float* __restrict__ wlin, const float* __restrict__ blin,
               float* __restrict__ hbufs, float* __restrict__ cbufs,
               const u64* __restrict__ partials, const float* __restrict__ Lb,
               int t) {
  __shared__ __align__(16) float xs[XDIM];
  __shared__ __align__(16) float hs[HIDDEN];
  __shared__ float sred[4];
  __shared__ u64 red[4];
  __shared__ u64 wbest[4];
  __shared__ int list[CAND_CAP];
  __shared__ int cnt;
  __shared__ int ptok_s;

  const int tid = threadIdx.x;
  const int lane = tid & 63;
  const int wid = tid >> 6;

  const float* hin = hbufs + (t & 1) * HIDDEN;
  const float* cin = cbufs + (t & 1) * HIDDEN;
  float* hout = hbufs + ((t + 1) & 1) * HIDDEN;
  float* cout = cbufs + ((t + 1) & 1) * HIDDEN;

  for (int i = tid; i < HIDDEN; i += 256) hs[i] = hin[i];
  if (tid == 0) cnt = 0;
  __syncthreads();

  int ptok = 0;
  if (t > 0) {
    // S = sum |h| for the quantization error bound
    float s = 0.f;
    for (int i = tid; i < HIDDEN; i += 256) s += fabsf(hs[i]);
    s = wave_reduce_sum(s);
    // reduce 256 bf16-screen partial maxima (set written by screen(t-1))
    u64 v = partials[((t + 1) & 1) * 256 + tid];
    v = wave_reduce_max_u64(v);
    if (lane == 0) {
      sred[wid] = s;
      red[wid] = v;
    }
    __syncthreads();
    const float S = sred[0] + sred[1] + sred[2] + sred[3];
    u64 m = red[0];
    if (red[1] > m) m = red[1];
    if (red[2] > m) m = red[2];
    if (red[3] > m) m = red[3];
    const int mrow = VOCAB - (int)(u32)(m & 0xFFFFFFFFu);
    const float maxb = Lb[mrow];
    // |logit_bf16 - logit_fp32| <= S * (1/32) * 2^-8  (+ fp32 accum margin)
    const float thr = maxb - 2.0f * (S * 1.220703125e-4f) - 2e-3f;
    for (int r = tid; r < VOCAB; r += 256) {
      if (Lb[r] >= thr) {
        int ix = atomicAdd(&cnt, 1);
        if (ix < CAND_CAP) list[ix] = r;
      }
    }
    __syncthreads();
    const int nc = (cnt < CAND_CAP) ? cnt : CAND_CAP;
    // exact fp32 recompute of candidates, one wave per candidate
    u64 best = 0;
    for (int ci = wid; ci < nc; ci += 4) {
      const int row = list[ci];
      const float4* wr = (const float4*)(wlin + (size_t)row * HIDDEN);
      float a = 0.f;
#pragma unroll
      for (int i = 0; i < 4; ++i) {
        const int k = lane + i * 64;
        float4 w4 = wr[k];
        float4 h4 = *((const float4*)&hs[k * 4]);
        a += w4.x * h4.x + w4.y * h4.y + w4.z * h4.z + w4.w * h4.w;
      }
      a = wave_reduce_sum(a);
      if (lane == 0) {
        u64 pk = ((u64)fmono(a + blin[row]) << 32) | (u32)(VOCAB - row);
        if (pk > best) best = pk;
      }
    }
    if (lane == 0) wbest[wid] = best;
    __syncthreads();
    if (tid == 0) {
      u64 b2 = wbest[0];
      if (wbest[1] > b2) b2 = wbest[1];
      if (wbest[2] > b2) b2 = wbest[2];
      if (wbest[3] > b2) b2 = wbest[3];
      ptok_s = (b2 == 0ull) ? 0 : (VOCAB - (int)(u32)(b2 & 0xFFFFFFFFu));
    }
    __syncthreads();
    ptok = ptok_s;
  }

  // stage x = [prev_embed, tok_embed]
  const int tok = seq[t];
  for (int i = tid; i < EMBED; i += 256) {
    xs[i] = (t == 0) ? 0.0f : emb[(size_t)ptok * EMBED + i];
    xs[EMBED + i] = emb[(size_t)tok * EMBED + i];
  }
  __syncthreads();

  // gates: each wave computes rows {j, j+H, j+2H, j+3H}
  const int j = blockIdx.x * 4 + wid;
  float acc[4];
#pragma unroll
  for (int g = 0; g < 4; ++g) {
    const float4* wx = (const float4*)(wih + (size_t)(g * HIDDEN + j) * XDIM);
    const float4* wh = (const float4*)(whh + (size_t)(g * HIDDEN + j) * HIDDEN);
    float a = 0.f;
#pragma unroll
    for (int i = 0; i < 4; ++i) {
      const int k = lane + i * 64;
      float4 w4 = wx[k];
      float4 x4 = *((const float4*)&xs[k * 4]);
      a += w4.x * x4.x + w4.y * x4.y + w4.z * x4.z + w4.w * x4.w;
      float4 v4 = wh[k];
      float4 h4 = *((const float4*)&hs[k * 4]);
      a += v4.x * h4.x + v4.y * h4.y + v4.z * h4.z + v4.w * h4.w;
    }
    acc[g] = wave_reduce_sum(a);
  }

  if (lane == 0) {
    float gi = acc[0] + bih[j] + bhh[j];
    float gf = acc[1] + bih[HIDDEN + j] + bhh[HIDDEN + j];
    float gg = acc[2] + bih[2 * HIDDEN + j] + bhh[2 * HIDDEN + j];
    float go = acc[3] + bih[3 * HIDDEN + j] + bhh[3 * HIDDEN + j];
    float si = 1.0f / (1.0f + expf(-gi));
    float sf = 1.0f / (1.0f + expf(-gf));
    float tg = tanhf(gg);
    float so = 1.0f / (1.0f + expf(-go));
    float c2 = sf * cin[j] + si * tg;
    float h2 = so * tanhf(c2);
    cout[j] = c2;
    hout[j] = h2;
  }
}

// bf16 screen: Lb = W_bf16 @ h + b for all rows; per-block packed max ->
// partials[t&1]. Also resets the opposite parity set for screen(t+1).
// 8 rows per wave with h held in registers (no LDS bank conflicts).
__global__ __launch_bounds__(256)
void logits_screen(const u16* __restrict__ wb, const float* __restrict__ blin,
                   const float* __restrict__ hbufs, float* __restrict__ Lb,
                   u64* __restrict__ partials, int t) {
  __shared__ u64 red[4];
  const int tid = threadIdx.x;
  const int lane = tid & 63;
  const int wid = tid >> 6;

  const float* h = hbufs + ((t + 1) & 1) * HIDDEN;

  if (blockIdx.x == 0) partials[(((t & 1) ^ 1) << 8) + tid] = 0ull;

  // lane covers h[8k..8k+8) for k = lane and k = lane+64
  const float4* h4p = (const float4*)h;
  const float4 ha0 = h4p[2 * lane];
  const float4 ha1 = h4p[2 * lane + 1];
  const float4 hb0 = h4p[2 * (lane + 64)];
  const float4 hb1 = h4p[2 * (lane + 64) + 1];

  const int row0 = blockIdx.x * 32 + wid * 8;
  u64 best = 0;
#pragma unroll
  for (int r = 0; r < 8; ++r) {
    const int row = row0 + r;
    if (row >= VOCAB) break;
    const float4* wr = (const float4*)(wb + (size_t)row * HIDDEN);
    float a = 0.f;
    float4 w4 = wr[lane];
    u32 u;
    u = __float_as_uint(w4.x);
    a += __uint_as_float(u << 16) * ha0.x + __uint_as_float(u & 0xFFFF0000u) * ha0.y;
    u = __float_as_uint(w4.y);
    a += __uint_as_float(u << 16) * ha0.z + __uint_as_float(u & 0xFFFF0000u) * ha0.w;
    u = __float_as_uint(w4.z);
    a += __uint_as_float(u << 16) * ha1.x + __uint_as_float(u & 0xFFFF0000u) * ha1.y;
    u = __float_as_uint(w4.w);
    a += __uint_as_float(u << 16) * ha1.z + __uint_as_float(u & 0xFFFF0000u) * ha1.w;
    w4 = wr[lane + 64];
    u = __float_as_uint(w4.x);
    a += __uint_as_float(u << 16) * hb0.x + __uint_as_float(u & 0xFFFF0000u) * hb0.y;
    u = __float_as_uint(w4.y);
    a += __uint_as_float(u << 16) * hb0.z + __uint_as_float(u & 0xFFFF0000u) * hb0.w;
    u = __float_as_uint(w4.z);
    a += __uint_as_float(u << 16) * hb1.x + __uint_as_float(u & 0xFFFF0000u) * hb1.y;
    u = __float_as_uint(w4.w);
    a += __uint_as_float(u << 16) * hb1.z + __uint_as_float(u & 0xFFFF0000u) * hb1.w;

    a = wave_reduce_sum(a);
    if (lane == 0) {
      float lg = a + blin[row];
      Lb[row] = lg;
      u64 pk = ((u64)fmono(lg) << 32) | (u32)(VOCAB - row);
      if (pk > best) best = pk;
    }
  }
  if (lane == 0) red[wid] = best;
  __syncthreads();
  if (tid == 0) {
    u64 m = red[0];
    if (red[1] > m) m = red[1];
    if (red[2] > m) m = red[2];
    if (red[3] > m) m = red[3];
    atomicMax(&partials[((t & 1) << 8) + (blockIdx.x & 255)], m);
  }
}

// exact fp32 logits of the final step -> d_out (identical dot to round 0)
__global__ __launch_bounds__(256)
void logits_out(const float* __restrict__ wlin, const float* __restrict__ blin,
                const float* __restrict__ h, float* __restrict__ out) {
  __shared__ __align__(16) float hs[HIDDEN];
  const int tid = threadIdx.x;
  const int lane = tid & 63;
  const int wid = tid >> 6;
  for (int i = tid; i < HIDDEN; i += 256) hs[i] = h[i];
  __syncthreads();
  const int row = blockIdx.x * 4 + wid;
  if (row < VOCAB) {
    const float4* wr = (const float4*)(wlin + (size_t)row * HIDDEN);
    float a = 0.f;
#pragma unroll
    for (int i = 0; i < 4; ++i) {
      const int k = lane + i * 64;
      float4 w4 = wr[k];
      float4 h4 = *((const float4*)&hs[k * 4]);
      a += w4.x * h4.x + w4.y * h4.y + w4.z * h4.z + w4.w * h4.w;
    }
    a = wave_reduce_sum(a);
    if (lane == 0) out[row] = a + blin[row];
  }
}

// ====================== fallback (round-0) path ======================

__global__ __launch_bounds__(256)
void lstm_step_v0(const float* __restrict__ emb,
                  const float* __restrict__ wih, const float* __restrict__ whh,
                  const float* __restrict__ bih, const float* __restrict__ bhh,
                  const int* __restrict__ seq,
                  float* __restrict__ hbufs, float* __restrict__ cbufs,
                  u64* __restrict__ partials, int t) {
  __shared__ __align__(16) float xs[XDIM];
  __shared__ __align__(16) float hs[HIDDEN];
  __shared__ u64 red[4];
  __shared__ int ptok_s;

  const int tid = threadIdx.x;
  const int lane = tid & 63;
  const int wid = tid >> 6;

  const float* hin = hbufs + (t & 1) * HIDDEN;
  const float* cin = cbufs + (t & 1) * HIDDEN;
  float* hout = hbufs + ((t + 1) & 1) * HIDDEN;
  float* cout = cbufs + ((t + 1) & 1) * HIDDEN;

  int ptok = -1;
  if (t > 0) {
    const u64* part = partials + ((t + 1) & 1) * 256;
    u64 v = wave_reduce_max_u64(part[tid]);
    if (lane == 0) red[wid] = v;
    __syncthreads();
    if (tid == 0) {
      u64 m = red[0];
      if (red[1] > m) m = red[1];
      if (red[2] > m) m = red[2];
      if (red[3] > m) m = red[3];
      ptok_s = VOCAB - (int)(u32)(m & 0xFFFFFFFFu);
    }
    __syncthreads();
    ptok = ptok_s;
  }
  if (blockIdx.x == 0) partials[(t & 1) * 256 + tid] = 0ull;

  const int tok = seq[t];
  for (int i = tid; i < EMBED; i += 256) {
    xs[i] = (t == 0) ? 0.0f : emb[(size_t)ptok * EMBED + i];
    xs[EMBED + i] = emb[(size_t)tok * EMBED + i];
  }
  for (int i = tid; i < HIDDEN; i += 256) hs[i] = hin[i];
  __syncthreads();

  const int j = blockIdx.x * 4 + wid;
  float acc[4];
#pragma unroll
  for (int g = 0; g < 4; ++g) {
    const float4* wx = (const float4*)(wih + (size_t)(g * HIDDEN + j) * XDIM);
    const float4* wh = (const float4*)(whh + (size_t)(g * HIDDEN + j) * HIDDEN);
    float a = 0.f;
#pragma unroll
    for (int i = 0; i < 4; ++i) {
      const int k = lane + i * 64;
      float4 w4 = wx[k];
      float4 x4 = *((const float4*)&xs[k * 4]);
      a += w4.x * x4.x + w4.y * x4.y + w4.z * x4.z + w4.w * x4.w;
      float4 v4 = wh[k];
      float4 h4 = *((const float4*)&hs[k * 4]);
      a += v4.x * h4.x + v4.y * h4.y + v4.z * h4.z + v4.w * h4.w;
    }
    acc[g] = wave_reduce_sum(a);
  }

  if (lane == 0) {
    float gi = acc[0] + bih[j] + bhh[j];
    float gf = acc[1] + bih[HIDDEN + j] + bhh[HIDDEN + j];
    float gg = acc[2] + bih[2 * HIDDEN + j] + bhh[2 * HIDDEN + j];
    float go = acc[3] + bih[3 * HIDDEN + j] + bhh[3 * HIDDEN + j];
    float si = 1.0f / (1.0f + expf(-gi));
    float sf = 1.0f / (1.0f + expf(-gf));
    float tg = tanhf(gg);
    float so = 1.0f / (1.0f + expf(-go));
    float c2 = sf * cin[j] + si * tg;
    float h2 = so * tanhf(c2);
    cout[j] = c2;
    hout[j] = h2;
  }
}

__global__ __launch_bounds__(256)
void logits_step_v0(const float* __restrict__ wlin, const float* __restrict__ blin,
                    const float* __restrict__ hbufs, float* __restrict__ out,
                    u64* __restrict__ partials, int t) {
  __shared__ __align__(16) float hs[HIDDEN];
  __shared__ u64 red[4];
  const int tid = threadIdx.x;
  const int lane = tid & 63;
  const int wid = tid >> 6;

  const float* h = hbufs + ((t + 1) & 1) * HIDDEN;
  for (int i = tid; i < HIDDEN; i += 256) hs[i] = h[i];
  __syncthreads();

  const int row = blockIdx.x * 4 + wid;
  u64 pk = 0ull;
  if (row < VOCAB) {
    const float4* wr = (const float4*)(wlin + (size_t)row * HIDDEN);
    float a = 0.f;
#pragma unroll
    for (int i = 0; i < 4; ++i) {
      const int k = lane + i * 64;
      float4 w4 = wr[k];
      float4 h4 = *((const float4*)&hs[k * 4]);
      a += w4.x * h4.x + w4.y * h4.y + w4.z * h4.z + w4.w * h4.w;
    }
    a = wave_reduce_sum(a);
    if (lane == 0) {
      float logit = a + blin[row];
      out[row] = logit;
      pk = ((u64)fmono(logit) << 32) | (u32)(VOCAB - row);
    }
  }
  if (lane == 0) red[wid] = pk;
  __syncthreads();
  if (tid == 0) {
    u64 m = red[0];
    if (red[1] > m) m = red[1];
    if (red[2] > m) m = red[2];
    if (red[3] > m) m = red[3];
    atomicMax(&partials[(t & 1) * 256 + (blockIdx.x & 255)], m);
  }
}

extern "C" void kernel_launch(void* const* d_in, const int* in_sizes, int n_in,
                              void* d_out, int out_size, void* d_ws, size_t ws_size,
                              hipStream_t stream) {
  const int* seq = (const int*)d_in[0];
  const float* h0 = (const float*)d_in[1];
  const float* c0 = (const float*)d_in[2];
  const float* emb = (const float*)d_in[3];
  const float* wih = (const float*)d_in[4];
  const float* whh = (const float*)d_in[5];
  const float* bih = (const float*)d_in[6];
  const float* bhh = (const float*)d_in[7];
  const float* wlin = (const float*)d_in[8];
  const float* blin = (const float*)d_in[9];
  float* out = (float*)d_out;

  // ws layout
  const size_t OFF_H = 4096;                 // partials: 2*256 u64
  const size_t OFF_C = OFF_H + 8192;         // hbufs: 2*1024 f
  const size_t OFF_LB = OFF_C + 8192;        // cbufs: 2*1024 f
  const size_t OFF_WB = OFF_LB + 201216;     // Lb: VOCAB f (padded)
  const size_t NEED = OFF_WB + (size_t)VOCAB * HIDDEN * 2;

  u64* partials = (u64*)d_ws;
  float* hbufs = (float*)((char*)d_ws + OFF_H);
  float* cbufs = (float*)((char*)d_ws + OFF_C);
  float* Lb = (float*)((char*)d_ws + OFF_LB);
  u16* wb = (u16*)((char*)d_ws + OFF_WB);

  if (ws_size >= NEED) {
    init_state<<<1, 1024, 0, stream>>>(h0, c0, hbufs, cbufs, partials);
    const long long n8 = (long long)VOCAB * HIDDEN / 8;
    convert_wlin<<<(int)((n8 + 255) / 256), 256, 0, stream>>>(wlin, wb);
    for (int t = 0; t < SEQLEN; ++t) {
      lstm_step<<<HIDDEN / 4, 256, 0, stream>>>(emb, wih, whh, bih, bhh, seq,
                                                wlin, blin, hbufs, cbufs,
                                                partials, Lb, t);
      if (t < SEQLEN - 1)
        logits_screen<<<(VOCAB + 31) / 32, 256, 0, stream>>>(wb, blin, hbufs,
                                                             Lb, partials, t);
    }
    // final h lives at parity (511+1)&1 == 0
    logits_out<<<(VOCAB + 3) / 4, 256, 0, stream>>>(wlin, blin, hbufs, out);
  } else {
    // fallback: round-0 fp32 path
    init_state<<<1, 1024, 0, stream>>>(h0, c0, hbufs, cbufs, partials);
    for (int t = 0; t < SEQLEN; ++t) {
      lstm_step_v0<<<HIDDEN / 4, 256, 0, stream>>>(emb, wih, whh, bih, bhh, seq,
                                                   hbufs, cbufs, partials, t);
      logits_step_v0<<<(VOCAB + 3) / 4, 256, 0, stream>>>(wlin, blin, hbufs, out,
                                                          partials, t);
    }
  }
}